// Round 13
// baseline (442.962 us; speedup 1.0000x reference)
//
#include <hip/hip_runtime.h>
#include <hip/hip_bf16.h>

#define B_ 2
#define S_ 1024
#define D_ 768
#define H_ 12
#define F_ 6
#define DH_ 64
#define BS_ (B_*S_)   // 2048
#define D2_ (2*D_)    // 1536
#define FD_ (F_*D_)   // 4608
#define FD4_ (FD_/4)  // 1152

typedef __attribute__((ext_vector_type(8))) short bf16x8;
typedef __attribute__((ext_vector_type(4))) short bf16x4;
typedef __attribute__((ext_vector_type(4))) float f32x4;

__device__ __forceinline__ float gelu_exact(float x) {
    return 0.5f * x * (1.0f + erff(x * 0.70710678118654752f));
}

// fp32 -> bf16 bits, round-to-nearest-even
__device__ __forceinline__ short f2bf(float f) {
    union { float f; unsigned u; } v; v.f = f;
    unsigned r = v.u + 0x7fff + ((v.u >> 16) & 1);
    return (short)(r >> 16);
}
// truncating fp32->bf16 (1 op)
__device__ __forceinline__ short f2bf_t(float f) {
    return (short)(__float_as_uint(f) >> 16);
}
__device__ __forceinline__ float bf2f(short b) {
    union { unsigned u; float f; } v;
    v.u = ((unsigned)(unsigned short)b) << 16;
    return v.f;
}
// bare v_exp_f32 (2^x, flush-to-zero below 2^-126 — fine for softmax)
__device__ __forceinline__ float fast_exp2(float x) {
#if __has_builtin(__builtin_amdgcn_exp2f)
    return __builtin_amdgcn_exp2f(x);
#else
    float r; asm("v_exp_f32 %0, %1" : "=v"(r) : "v"(x)); return r;
#endif
}

// ===========================================================================
// Shared GEMM tile machinery (128x128 tile, BK=64, 4 waves 2x2, prefetch).
// LDS layout: [tile(8)][kchunk(8)][slot(16)] x 8 shorts, slot = l15^kc^tile.
// ===========================================================================

#define GEMM_STAGE_A16(av)                                                    \
    {                                                                         \
        _Pragma("unroll")                                                     \
        for (int c = 0; c < 4; c++) {                                         \
            const int kc = (akb >> 3) + c;                                    \
            *(bf16x8*)&As[((amt*8 + kc)*16 + ((ar15 ^ kc ^ amt) & 15))*8] = (av)[c]; \
        }                                                                     \
    }

#define GEMM_STAGE_B16(bv)                                                    \
    {                                                                         \
        _Pragma("unroll")                                                     \
        for (int j = 0; j < 4; j++) {                                         \
            const int n  = bn0 + j;                                           \
            const int nt = n >> 4;                                            \
            bf16x8 s;                                                         \
            _Pragma("unroll")                                                 \
            for (int r = 0; r < 8; r++) s[r] = (bv)[r][j];                    \
            *(bf16x8*)&Bs[((nt*8 + bkg)*16 + (((n & 15) ^ bkg ^ nt) & 15))*8] = s; \
        }                                                                     \
    }

#define GEMM_LOAD_A16(av, kb)                                                 \
    {                                                                         \
        _Pragma("unroll")                                                     \
        for (int c = 0; c < 4; c++)                                           \
            (av)[c] = *(const bf16x8*)(Ap + (kb) + c*8);                      \
    }

#define GEMM_LOAD_B16(bv, kb, strideN)                                        \
    {                                                                         \
        _Pragma("unroll")                                                     \
        for (int r = 0; r < 8; r++)                                           \
            *(bf16x4*)&(bv)[r][0] = *(const bf16x4*)(Wp + (long)((kb) + r) * (strideN)); \
    }

#define GEMM_COMPUTE()                                                        \
    {                                                                         \
        _Pragma("unroll")                                                     \
        for (int ks = 0; ks < 2; ks++) {                                      \
            const int kc = ks*4 + quad;                                       \
            bf16x8 af[4], bf[4];                                              \
            _Pragma("unroll")                                                 \
            for (int mt = 0; mt < 4; mt++) {                                  \
                const int MT = wr*4 + mt;                                     \
                af[mt] = *(const bf16x8*)&As[((MT*8 + kc)*16 + ((l15 ^ kc ^ MT) & 15))*8]; \
            }                                                                 \
            _Pragma("unroll")                                                 \
            for (int nt = 0; nt < 4; nt++) {                                  \
                const int NT = wc*4 + nt;                                     \
                bf[nt] = *(const bf16x8*)&Bs[((NT*8 + kc)*16 + ((l15 ^ kc ^ NT) & 15))*8]; \
            }                                                                 \
            _Pragma("unroll")                                                 \
            for (int mt = 0; mt < 4; mt++)                                    \
                _Pragma("unroll")                                             \
                for (int nt = 0; nt < 4; nt++)                                \
                    acc[mt][nt] = __builtin_amdgcn_mfma_f32_16x16x32_bf16(    \
                        af[mt], bf[nt], acc[mt][nt], 0, 0, 0);                \
        }                                                                     \
    }

#define GEMM_COMMON_IDS()                                                     \
    const int tid  = threadIdx.x;                                             \
    const int wave = tid >> 6;                                                \
    const int lane = tid & 63;                                                \
    const int l15  = lane & 15;                                               \
    const int quad = lane >> 4;                                               \
    const int wr   = wave >> 1;                                               \
    const int wc   = wave & 1;                                                \
    const int ar   = tid >> 1;                                                \
    const int akb  = (tid & 1) * 32;                                          \
    const int amt  = ar >> 4;                                                 \
    const int ar15 = ar & 15;                                                 \
    const int bn0  = (tid & 31) * 4;                                          \
    const int bkg  = tid >> 5;

// B load/stage helpers for mfma_gemm (B16: prepacked bf16 W; else fp32 W)
template<int B16>
__device__ __forceinline__ void gemm_load_b(
    const void* __restrict__ Wv, long rowOff, int N, int kb,
    float bf[8][4], short bh[8][4])
{
    if constexpr (B16) {
        const short* Wp = (const short*)Wv + rowOff;
        #pragma unroll
        for (int r = 0; r < 8; r++)
            *(bf16x4*)&bh[r][0] = *(const bf16x4*)(Wp + (long)(kb + r) * N);
    } else {
        const float* Wp = (const float*)Wv + rowOff;
        #pragma unroll
        for (int r = 0; r < 8; r++)
            *(float4*)&bf[r][0] = *(const float4*)(Wp + (long)(kb + r) * N);
    }
}

template<int B16>
__device__ __forceinline__ void gemm_stage_b(
    short* Bs, int bn0, int bkg, const float bf[8][4], const short bh[8][4])
{
    #pragma unroll
    for (int j = 0; j < 4; j++) {
        const int n  = bn0 + j;
        const int nt = n >> 4;
        bf16x8 s;
        #pragma unroll
        for (int r = 0; r < 8; r++) s[r] = B16 ? bh[r][j] : f2bf_t(bf[r][j]);
        *(bf16x8*)&Bs[((nt*8 + bkg)*16 + (((n & 15) ^ bkg ^ nt) & 15))*8] = s;
    }
}

// ---------------------------------------------------------------------------
// prepack: fp32 -> bf16 for x, W_kv, W_q, W_g1, W_m1 (multi-read operands).
// ---------------------------------------------------------------------------
#define PPK_N0 393216    // x        1572864 f /4
#define PPK_N1 294912    // W_kv     1179648 f /4
#define PPK_N2 884736    // W_q      3538944 f /4
#define PPK_N3 221184    // W_g1      884736 f /4
#define PPK_N4 1769472   // W_m1     7077888 f /4
__global__ __launch_bounds__(256) void prepack(
    const float* __restrict__ x, const float* __restrict__ Wkv,
    const float* __restrict__ Wq, const float* __restrict__ Wg1,
    const float* __restrict__ Wm1,
    short* __restrict__ xb, short* __restrict__ wkvb,
    short* __restrict__ wqb, short* __restrict__ wg1b,
    short* __restrict__ wmb)
{
    long idx = (long)blockIdx.x * 256 + threadIdx.x;
    const float* src; short* dst;
    if (idx < PPK_N0) { src = x; dst = xb; }
    else if ((idx -= PPK_N0) < PPK_N1) { src = Wkv; dst = wkvb; }
    else if ((idx -= PPK_N1) < PPK_N2) { src = Wq;  dst = wqb; }
    else if ((idx -= PPK_N2) < PPK_N3) { src = Wg1; dst = wg1b; }
    else { idx -= PPK_N3; src = Wm1; dst = wmb; }
    float4 v = ((const float4*)src)[idx];
    bf16x4 o;
    o[0] = f2bf(v.x); o[1] = f2bf(v.y); o[2] = f2bf(v.z); o[3] = f2bf(v.w);
    ((bf16x4*)dst)[idx] = o;
}

// prepack_w2: W_m2 fp32 -> bf16 into wmb (reuses W_m1's buffer after gemm5)
__global__ __launch_bounds__(256) void prepack_w2(
    const float* __restrict__ Wm2, short* __restrict__ wmb)
{
    long idx = (long)blockIdx.x * 256 + threadIdx.x;
    float4 v = ((const float4*)Wm2)[idx];
    bf16x4 o;
    o[0] = f2bf(v.x); o[1] = f2bf(v.y); o[2] = f2bf(v.z); o[3] = f2bf(v.w);
    ((bf16x4*)wmb)[idx] = o;
}

// ---------------------------------------------------------------------------
// mfma_gemm: bf16 A; W either prepacked bf16 (B16=1) or fp32 (B16=0);
// output bf16 (OUT16=1) or fp32 (OUT16=0).
// MODE 2: C = bf2f(addend) + (*scale_ptr)*v ; MODE 4: raw split-K partial
// ---------------------------------------------------------------------------
template<int MODE, int B16, int OUT16>
__global__ __launch_bounds__(256, 2) void mfma_gemm(
    const short* __restrict__ A, const void* __restrict__ Wv,
    const float* __restrict__ bias, void* __restrict__ Cv,
    int M, int N, int K, int kLen,
    long cStrideZ, long kStrideZ,
    const short* __restrict__ addend, const float* __restrict__ scale_ptr)
{
    short* C16 = (short*)Cv;
    float* C32 = (float*)Cv;
    if (blockIdx.z) { C16 += blockIdx.z * cStrideZ; C32 += blockIdx.z * cStrideZ; }
    const int kBeg = (int)(blockIdx.z * kStrideZ);
    const int kEnd = kBeg + kLen;

    __shared__ __align__(16) short As[8192];
    __shared__ __align__(16) short Bs[8192];

    GEMM_COMMON_IDS();

    const int m0 = blockIdx.y * 128;
    const int n0 = blockIdx.x * 128;

    const short* Ap = A + (long)(m0 + ar) * K + akb;
    const long wRowOff = (long)(bkg * 8) * N + n0 + bn0;

    f32x4 acc[4][4];
    #pragma unroll
    for (int i = 0; i < 4; i++)
        #pragma unroll
        for (int j = 0; j < 4; j++)
            acc[i][j] = (f32x4){0.f, 0.f, 0.f, 0.f};

    bf16x8 a0[4], a1[4];
    float bf0[8][4], bf1[8][4];
    short bh0[8][4], bh1[8][4];
    GEMM_LOAD_A16(a0, kBeg);
    gemm_load_b<B16>(Wv, wRowOff, N, kBeg, bf0, bh0);

    for (int kb = kBeg; kb < kEnd; kb += 128) {
        GEMM_STAGE_A16(a0);
        gemm_stage_b<B16>(Bs, bn0, bkg, bf0, bh0);
        __syncthreads();
        GEMM_LOAD_A16(a1, kb + 64);
        gemm_load_b<B16>(Wv, wRowOff, N, kb + 64, bf1, bh1);
        GEMM_COMPUTE();
        __syncthreads();
        GEMM_STAGE_A16(a1);
        gemm_stage_b<B16>(Bs, bn0, bkg, bf1, bh1);
        __syncthreads();
        if (kb + 128 < kEnd) {
            GEMM_LOAD_A16(a0, kb + 128);
            gemm_load_b<B16>(Wv, wRowOff, N, kb + 128, bf0, bh0);
        }
        GEMM_COMPUTE();
        __syncthreads();
    }

    float scale = 0.0f;
    if (MODE == 2) scale = *scale_ptr;
    #pragma unroll
    for (int nt = 0; nt < 4; nt++) {
        const int col = n0 + wc*64 + nt*16 + l15;
        const float bcol = (MODE == 4) ? 0.0f : bias[col];
        #pragma unroll
        for (int mt = 0; mt < 4; mt++) {
            #pragma unroll
            for (int r = 0; r < 4; r++) {
                const long row = m0 + wr*64 + mt*16 + quad*4 + r;
                float v = acc[mt][nt][r] + bcol;
                if (MODE == 2) v = bf2f(addend[row*N + col]) + scale * v;
                if (OUT16) C16[row*N + col] = f2bf(v);
                else       C32[row*N + col] = v;
            }
        }
    }
}

// ---------------------------------------------------------------------------
// xproj: fused projections of x — all-bf16 operands (prepacked).
//   tiles  0..11 -> kv fp32 [B*S,1536]
//   tiles 12..47 -> q bf16 pre-scaled*(0.125*log2e) -> qb [F][B][H][S][64]
//   tiles 48..56 -> g1 = gelu(..) fp32 [B*S,1152]
// ---------------------------------------------------------------------------
#define QSCALE 0.18033688011112042f   // 0.125 * log2(e)
__global__ __launch_bounds__(256, 2) void xproj_gemm(
    const short* __restrict__ xb,
    const short* __restrict__ W_kv, const float* __restrict__ b_kv, float* __restrict__ bufKV,
    const short* __restrict__ W_q,  const float* __restrict__ b_q,  short* __restrict__ qb,
    const short* __restrict__ W_g1, const float* __restrict__ b_g1, float* __restrict__ bufG1)
{
    __shared__ __align__(16) short As[8192];
    __shared__ __align__(16) short Bs[8192];

    GEMM_COMMON_IDS();

    const int ntile = blockIdx.x;
    const int m0 = blockIdx.y * 128;

    const short* Wseg; const float* bseg; float* Cseg = nullptr;
    int Nw, ncol, fidx = 0, mode;   // mode 0=kv,1=q,2=g1
    if (ntile < 12) {
        Wseg = W_kv; bseg = b_kv; Cseg = bufKV; Nw = 1536; ncol = ntile * 128; mode = 0;
    } else if (ntile < 48) {
        const int t = ntile - 12; fidx = t / 6;
        ncol = (t % 6) * 128;
        Wseg = W_q + (long)fidx * D_ * D_; bseg = b_q + fidx * D_;
        Nw = 768; mode = 1;
    } else {
        const int t = ntile - 48;
        Wseg = W_g1; bseg = b_g1; Cseg = bufG1; Nw = 1152; ncol = t * 128; mode = 2;
    }

    const short* Ap = xb + (long)(m0 + ar) * D_ + akb;
    const short* Wp = Wseg + (long)(bkg * 8) * Nw + ncol + bn0;

    f32x4 acc[4][4];
    #pragma unroll
    for (int i = 0; i < 4; i++)
        #pragma unroll
        for (int j = 0; j < 4; j++)
            acc[i][j] = (f32x4){0.f, 0.f, 0.f, 0.f};

    bf16x8 a0[4], a1[4];
    short b0[8][4], b1[8][4];
    GEMM_LOAD_A16(a0, 0);
    GEMM_LOAD_B16(b0, 0, Nw);

    for (int kb = 0; kb < D_; kb += 128) {
        GEMM_STAGE_A16(a0); GEMM_STAGE_B16(b0);
        __syncthreads();
        GEMM_LOAD_A16(a1, kb + 64);
        GEMM_LOAD_B16(b1, kb + 64, Nw);
        GEMM_COMPUTE();
        __syncthreads();
        GEMM_STAGE_A16(a1); GEMM_STAGE_B16(b1);
        __syncthreads();
        if (kb + 128 < D_) {
            GEMM_LOAD_A16(a0, kb + 128);
            GEMM_LOAD_B16(b0, kb + 128, Nw);
        }
        GEMM_COMPUTE();
        __syncthreads();
    }

    if (mode == 1) {
        const int bb = m0 >> 10;
        const int sBase = (m0 & 1023) + wr*64;
        #pragma unroll
        for (int nt = 0; nt < 4; nt++) {
            const int col = ncol + wc*64 + nt*16 + l15;   // 0..767
            const int hh = col >> 6, dd = col & 63;
            const float bcol = bseg[col];
            short* qBase = qb + ((((long)fidx*B_ + bb)*H_ + hh)*S_)*64 + dd;
            #pragma unroll
            for (int mt = 0; mt < 4; mt++) {
                #pragma unroll
                for (int r = 0; r < 4; r++) {
                    const int s = sBase + mt*16 + quad*4 + r;
                    qBase[(long)s*64] = f2bf((acc[mt][nt][r] + bcol) * QSCALE);
                }
            }
        }
    } else {
        #pragma unroll
        for (int nt = 0; nt < 4; nt++) {
            const int col = ncol + wc*64 + nt*16 + l15;
            const float bcol = bseg[col];
            #pragma unroll
            for (int mt = 0; mt < 4; mt++) {
                #pragma unroll
                for (int r = 0; r < 4; r++) {
                    const long row = m0 + wr*64 + mt*16 + quad*4 + r;
                    float v = acc[mt][nt][r] + bcol;
                    if (mode == 2) v = gelu_exact(v);
                    Cseg[row*Nw + col] = v;
                }
            }
        }
    }
}

// ---------------------------------------------------------------------------
// repack_kv: kv fp32 [B*S,1536] -> Kb bf16 [B][H][S][64], Vt bf16 [B][H][64][S]
// ---------------------------------------------------------------------------
__global__ __launch_bounds__(256) void repack_kv(
    const float* __restrict__ kvf, short* __restrict__ Kb, short* __restrict__ Vtb)
{
    __shared__ __align__(16) short T[64*64];
    const int bx = blockIdx.x;         // b*192 + h*16 + st
    const int st = bx & 15;
    const int h  = (bx >> 4) % 12;
    const int b  = bx / 192;
    const int tid = threadIdx.x;
    const int s_loc = tid & 63;
    const int dch  = (tid >> 6) * 16;
    const int s0 = st * 64;

    const float* kr = kvf + (long)(b*S_ + s0 + s_loc) * D2_ + h*64 + dch;
    float v[16];

    #pragma unroll
    for (int i = 0; i < 4; i++) *(float4*)&v[i*4] = *(const float4*)(kr + i*4);
    {
        short* kw = Kb + ((long)(b*H_ + h)*S_ + s0 + s_loc)*64 + dch;
        bf16x8 p0, p1;
        #pragma unroll
        for (int i = 0; i < 8; i++) { p0[i] = f2bf(v[i]); p1[i] = f2bf(v[8+i]); }
        *(bf16x8*)&kw[0] = p0;
        *(bf16x8*)&kw[8] = p1;
    }

    #pragma unroll
    for (int i = 0; i < 4; i++) *(float4*)&v[i*4] = *(const float4*)(kr + D_ + i*4);
    #pragma unroll
    for (int i = 0; i < 16; i++) {
        const int d = dch + i;
        T[d*64 + ((((s_loc >> 3) ^ d) & 7) << 3) + (s_loc & 7)] = f2bf(v[i]);
    }
    __syncthreads();
    const int d_loc = tid >> 2;
    const int sc = (tid & 3) * 16;
    const int c0 = sc >> 3;
    bf16x8 o0 = *(const bf16x8*)&T[d_loc*64 + (((c0 ^ d_loc) & 7) << 3)];
    bf16x8 o1 = *(const bf16x8*)&T[d_loc*64 + ((((c0+1) ^ d_loc) & 7) << 3)];
    short* vw = Vtb + ((long)(b*H_ + h)*64 + d_loc)*S_ + s0 + sc;
    *(bf16x8*)&vw[0] = o0;
    *(bf16x8*)&vw[8] = o1;
}

// ---------------------------------------------------------------------------
// MFMA flash attention v9: v8 + 2 q-tiles per block (128 q-rows).
// Each K/V stage+barrier now feeds 36 MFMAs (2x amortization); V fragments
// are read once per nt and used for both q-tiles; the two q-tiles give
// independent MFMA/exp chains (ILP). Grid 1152 < 6 blocks/CU x 256 = zero
// dispatch tail. LDS unchanged at 24 KB.
// ---------------------------------------------------------------------------
__global__ __launch_bounds__(256, 4) void attn_mfma9(
    const short* __restrict__ qb,
    const short* __restrict__ Kb,
    const short* __restrict__ Vt,
    short* __restrict__ stackedb)
{
    __shared__ __align__(16) short Ks[64*64];
    __shared__ __align__(16) short Vs[64*64];
    __shared__ __align__(16) short Ps[4][16*64];

    const int bx = blockIdx.x;
    const int qt = bx & 7;            // 8 q-tiles of 128 rows
    const int rest = bx >> 3;         // 0..143
    const int h = rest % 12;
    const int r2 = rest / 12;
    const int f = r2 % 6;
    const int b = r2 / 6;

    const int tid  = threadIdx.x;
    const int wave = tid >> 6;
    const int lane = tid & 63;
    const int l15  = lane & 15;
    const int quad = lane >> 4;

    const short* Kg = Kb + (long)(b*H_ + h) * S_ * 64;
    const short* Vg = Vt + (long)(b*H_ + h) * 64 * S_;

    // Q fragments: 2 row-tiles of 16 per wave (rows qt*128 + wave*32 + rt*16)
    bf16x8 aq[2][2];
    {
        const short* qp = qb + ((((long)f*B_ + b)*H_ + h)*S_ + qt*128 + wave*32)*64;
        #pragma unroll
        for (int rt = 0; rt < 2; rt++)
            #pragma unroll
            for (int ks = 0; ks < 2; ks++)
                aq[rt][ks] = *(const bf16x8*)&qp[(rt*16 + l15)*64 + ks*32 + quad*8];
    }

    bf16x8 onesf;
    {
        const short ONE = (short)0x3F80;
        #pragma unroll
        for (int j = 0; j < 8; j++) onesf[j] = (l15 == 0) ? ONE : (short)0;
    }

    const int skey = tid >> 2;         // staging row 0..63
    const int sch  = (tid & 3) * 2;    // chunk pair

    short* Psw = Ps[wave];

    f32x4 o[2][4], lo[2];
    #pragma unroll
    for (int rt = 0; rt < 2; rt++) {
        lo[rt] = (f32x4){0.f,0.f,0.f,0.f};
        #pragma unroll
        for (int nt = 0; nt < 4; nt++) o[rt][nt] = (f32x4){0.f,0.f,0.f,0.f};
    }

    bf16x8 kc[2], vc[2], kn[2], vn[2];
    #pragma unroll
    for (int j = 0; j < 2; j++) {
        const int ch = sch + j;
        kc[j] = *(const bf16x8*)&Kg[(long)skey*64 + ch*8];
        vc[j] = *(const bf16x8*)&Vg[(long)skey*S_ + ch*8];
    }

    for (int kt = 0; kt < 16; kt++) {
        #pragma unroll
        for (int j = 0; j < 2; j++) {
            const int ch = sch + j;
            const int slot = ((ch ^ skey) & 7) << 3;
            *(bf16x8*)&Ks[skey*64 + slot] = kc[j];
            *(bf16x8*)&Vs[skey*64 + slot] = vc[j];
        }
        __syncthreads();

        if (kt + 1 < 16) {
            #pragma unroll
            for (int j = 0; j < 2; j++) {
                const int ch = sch + j;
                kn[j] = *(const bf16x8*)&Kg[(long)((kt+1)*64 + skey)*64 + ch*8];
                vn[j] = *(const bf16x8*)&Vg[(long)skey*S_ + (kt+1)*64 + ch*8];
            }
        }

        // ---- per q-tile: S = Q@K^T, p = 2^s, P->LDS, P-frags back ----
        bf16x8 pa[2][2];
        #pragma unroll
        for (int rt = 0; rt < 2; rt++) {
            f32x4 st[4];
            #pragma unroll
            for (int nt = 0; nt < 4; nt++) st[nt] = (f32x4){0.f,0.f,0.f,0.f};
            #pragma unroll
            for (int nt = 0; nt < 4; nt++) {
                const int key = nt*16 + l15;
                #pragma unroll
                for (int ks = 0; ks < 2; ks++) {
                    const bf16x8 kf = *(const bf16x8*)
                        &Ks[key*64 + ((((ks*4 + quad) ^ key) & 7) << 3)];
                    st[nt] = __builtin_amdgcn_mfma_f32_16x16x32_bf16(
                        aq[rt][ks], kf, st[nt], 0, 0, 0);
                }
            }
            #pragma unroll
            for (int r = 0; r < 4; r++) {
                const int row = quad*4 + r;
                #pragma unroll
                for (int nt = 0; nt < 4; nt++) {
                    const float p = fast_exp2(st[nt][r]);
                    const int col = nt*16 + l15;
                    // rt=1 stored in the upper 8 rows of Psw? No — reuse the
                    // same 16x64 buffer: rt processed sequentially, and the
                    // pa reads below complete (same-wave lgkmcnt) before the
                    // next rt overwrites.
                    Psw[row*64 + ((((col >> 3) ^ row) & 7) << 3) + (col & 7)] = f2bf_t(p);
                }
            }
            #pragma unroll
            for (int ks = 0; ks < 2; ks++)
                pa[rt][ks] = *(const bf16x8*)
                    &Psw[l15*64 + ((((ks*4 + quad) ^ l15) & 7) << 3)];
        }

        // ---- O += P @ V (V frag shared across q-tiles); l += P @ ones ----
        #pragma unroll
        for (int nt = 0; nt < 4; nt++) {
            const int dim = nt*16 + l15;
            #pragma unroll
            for (int ks = 0; ks < 2; ks++) {
                const bf16x8 vf = *(const bf16x8*)
                    &Vs[dim*64 + ((((ks*4 + quad) ^ dim) & 7) << 3)];
                o[0][nt] = __builtin_amdgcn_mfma_f32_16x16x32_bf16(pa[0][ks], vf, o[0][nt], 0, 0, 0);
                o[1][nt] = __builtin_amdgcn_mfma_f32_16x16x32_bf16(pa[1][ks], vf, o[1][nt], 0, 0, 0);
            }
        }
        #pragma unroll
        for (int ks = 0; ks < 2; ks++) {
            lo[0] = __builtin_amdgcn_mfma_f32_16x16x32_bf16(pa[0][ks], onesf, lo[0], 0, 0, 0);
            lo[1] = __builtin_amdgcn_mfma_f32_16x16x32_bf16(pa[1][ks], onesf, lo[1], 0, 0, 0);
        }

        __syncthreads();
        #pragma unroll
        for (int j = 0; j < 2; j++) { kc[j] = kn[j]; vc[j] = vn[j]; }
    }

    #pragma unroll
    for (int rt = 0; rt < 2; rt++) {
        float inv[4];
        #pragma unroll
        for (int r = 0; r < 4; r++)
            inv[r] = 1.0f / __shfl(lo[rt][r], quad << 4);
        const long rowBase = (long)(b*S_ + qt*128 + wave*32 + rt*16 + quad*4);
        #pragma unroll
        for (int nt = 0; nt < 4; nt++) {
            #pragma unroll
            for (int r = 0; r < 4; r++) {
                stackedb[(rowBase + r)*FD_ + f*D_ + h*64 + nt*16 + l15] =
                    f2bf(o[rt][nt][r] * inv[r]);
            }
        }
    }
}

// ---------------------------------------------------------------------------
// gates[m,f] = softmax_f( g1[m,:] @ W_g2 + b_g2 ), one wave per row
// ---------------------------------------------------------------------------
__global__ __launch_bounds__(64) void gates_kernel(
    const float* __restrict__ g1, const float* __restrict__ W_g2,
    const float* __restrict__ b_g2, float* __restrict__ gates)
{
    const int m = blockIdx.x;
    const int lane = threadIdx.x;
    float p[6] = {0.f,0.f,0.f,0.f,0.f,0.f};
    for (int k = lane; k < FD4_; k += 64) {
        float g = g1[(long)m*FD4_ + k];
        #pragma unroll
        for (int f = 0; f < 6; f++) p[f] += g * W_g2[k*6 + f];
    }
    #pragma unroll
    for (int f = 0; f < 6; f++) {
        float v = p[f];
        #pragma unroll
        for (int off = 1; off < 64; off <<= 1) v += __shfl_xor(v, off);
        p[f] = v + b_g2[f];
    }
    float mx = p[0];
    #pragma unroll
    for (int f = 1; f < 6; f++) mx = fmaxf(mx, p[f]);
    float se = 0.f;
    #pragma unroll
    for (int f = 0; f < 6; f++) { p[f] = expf(p[f] - mx); se += p[f]; }
    const float inv = 1.0f / se;
    if (lane < 6) gates[m*6 + lane] = p[lane] * inv;
}

// ---------------------------------------------------------------------------
// reduce_m1: h1 = gelu(p0+p1+p2+bias) -> bf16 [2048,1536]; partials bf16
// ---------------------------------------------------------------------------
__global__ __launch_bounds__(256) void reduce_m1(
    const short* __restrict__ p, const float* __restrict__ bias,
    short* __restrict__ out)
{
    const int idx = blockIdx.x * 256 + threadIdx.x;
    const int col4 = idx % (D2_/4);
    const long MN4 = (long)BS_ * D2_ / 4;   // bf16x4 units per slice
    bf16x4 a = ((const bf16x4*)p)[idx];
    bf16x4 b = ((const bf16x4*)p)[idx + MN4];
    bf16x4 c = ((const bf16x4*)p)[idx + 2*MN4];
    float4 bb = ((const float4*)bias)[col4];
    bf16x4 o;
    o[0] = f2bf(gelu_exact(bf2f(a[0]) + bf2f(b[0]) + bf2f(c[0]) + bb.x));
    o[1] = f2bf(gelu_exact(bf2f(a[1]) + bf2f(b[1]) + bf2f(c[1]) + bb.y));
    o[2] = f2bf(gelu_exact(bf2f(a[2]) + bf2f(b[2]) + bf2f(c[2]) + bb.z));
    o[3] = f2bf(gelu_exact(bf2f(a[3]) + bf2f(b[3]) + bf2f(c[3]) + bb.w));
    ((bf16x4*)out)[idx] = o;
}

// ---------------------------------------------------------------------------
// comb[m,d] = sum_f mixed[m, f*768+d] * gates[m,f]  ; mixed bf16 -> comb bf16
// ---------------------------------------------------------------------------
__global__ __launch_bounds__(256) void combine_kernel(
    const short* __restrict__ mixedb, const float* __restrict__ gates,
    short* __restrict__ comb)
{
    const int idx = blockIdx.x * 256 + threadIdx.x;
    const int m = idx / 192;
    const int d4 = idx - m*192;
    const bf16x4* mrow = (const bf16x4*)(mixedb + (long)m * FD_);
    float4 a = {0.f,0.f,0.f,0.f};
    #pragma unroll
    for (int f = 0; f < 6; f++) {
        float g = gates[m*6 + f];
        bf16x4 v = mrow[f*192 + d4];
        a.x += g*bf2f(v[0]); a.y += g*bf2f(v[1]);
        a.z += g*bf2f(v[2]); a.w += g*bf2f(v[3]);
    }
    bf16x4 o;
    o[0] = f2bf(a.x); o[1] = f2bf(a.y); o[2] = f2bf(a.z); o[3] = f2bf(a.w);
    ((bf16x4*)comb)[idx] = o;
}

// ---------------------------------------------------------------------------
// reduce_ln: preY = x + p0 + p1 + b_out, then LayerNorm -> out. One block/row.
// ---------------------------------------------------------------------------
__global__ __launch_bounds__(256) void reduce_ln(
    const float* __restrict__ p, const float* __restrict__ bias,
    const float* __restrict__ x,
    const float* __restrict__ ln_g, const float* __restrict__ ln_b,
    float* __restrict__ out)
{
    __shared__ float red[8];
    const int m = blockIdx.x;
    const int tid = threadIdx.x;
    const long MN = (long)BS_ * D_;
    float vals[3];
    float s = 0.f, s2 = 0.f;
    #pragma unroll
    for (int i = 0; i < 3; i++) {
        const int d = tid + 256*i;
        const long o = (long)m*D_ + d;
        float v = x[o] + p[o] + p[MN + o] + bias[d];
        vals[i] = v;
        s += v; s2 += v*v;
    }
    #pragma unroll
    for (int off = 32; off >= 1; off >>= 1) {
        s  += __shfl_xor(s, off);
        s2 += __shfl_xor(s2, off);
    }
    const int wave = tid >> 6;
    if ((tid & 63) == 0) { red[wave*2] = s; red[wave*2+1] = s2; }
    __syncthreads();
    s  = red[0]+red[2]+red[4]+red[6];
    s2 = red[1]+red[3]+red[5]+red[7];
    const float mu  = s * (1.0f/D_);
    const float var = s2 * (1.0f/D_) - mu*mu;
    const float inv = rsqrtf(var + 1e-5f);
    #pragma unroll
    for (int i = 0; i < 3; i++) {
        const int d = tid + 256*i;
        out[(long)m*D_ + d] = (vals[i] - mu) * inv * ln_g[d] + ln_b[d];
    }
}

// ---------------------------------------------------------------------------
extern "C" void kernel_launch(void* const* d_in, const int* in_sizes, int n_in,
                              void* d_out, int out_size, void* d_ws, size_t ws_size,
                              hipStream_t stream)
{
    const float* x     = (const float*)d_in[0];
    const float* W_kv  = (const float*)d_in[1];
    const float* b_kv  = (const float*)d_in[2];
    const float* W_q   = (const float*)d_in[3];
    const float* b_q   = (const float*)d_in[4];
    const float* W_m1  = (const float*)d_in[5];
    const float* b_m1  = (const float*)d_in[6];
    const float* W_m2  = (const float*)d_in[7];
    const float* b_m2  = (const float*)d_in[8];
    const float* cross = (const float*)d_in[9];
    const float* W_g1  = (const float*)d_in[10];
    const float* b_g1  = (const float*)d_in[11];
    const float* W_g2  = (const float*)d_in[12];
    const float* b_g2  = (const float*)d_in[13];
    const float* W_out = (const float*)d_in[14];
    const float* b_out = (const float*)d_in[15];
    const float* ln_g  = (const float*)d_in[16];
    const float* ln_b  = (const float*)d_in[17];
    float* out = (float*)d_out;

    // workspace layout (float units), total ~88.3 MB:
    float* ws       = (float*)d_ws;
    float* bufA     = ws;
    float* bufB     = bufA + (size_t)4718592;
    short* stackedS = (short*)(bufB + (size_t)3145728);
    float* bufC     = (float*)(stackedS + (size_t)BS_*FD_);
    float* gates    = bufC + (size_t)BS_*FD4_;

    short* wpack = (short*)(gates + 12288);
    short* xb    = wpack;                                  // 1,572,864 sh
    short* wkvb  = xb + (size_t)BS_*D_;                    // 1,179,648 sh
    short* wqb   = wkvb + (size_t)D_*D2_;                  // 3,538,944 sh
    short* wg1b  = wqb + (size_t)F_*D_*D_;                 //   884,736 sh
    short* wmb   = wg1b + (size_t)D_*FD4_;                 // 7,077,888 sh

    short* qb      = (short*)bufA;
    short* m1part  = (short*)bufA;     // after qb is dead
    short* mixedb  = (short*)bufA;     // after partials are dead
    short* Kb      = (short*)bufC;
    short* Vt      = Kb + (size_t)B_*H_*S_*DH_;
    short* h1b     = (short*)bufB;
    short* combb   = (short*)bufC;
    float* outPart = (float*)stackedS;

    dim3 blk(256);

    // 0. prepack x + W_kv/W_q/W_g1/W_m1 to bf16
    prepack<<<dim3((PPK_N0+PPK_N1+PPK_N2+PPK_N3+PPK_N4)/256), blk, 0, stream>>>(
        x, W_kv, W_q, W_g1, W_m1, xb, wkvb, wqb, wg1b, wmb);
    // 1. fused x-projections (all-bf16): kv fp32, q bf16 (log2e-scaled), g1 fp32
    xproj_gemm<<<dim3(57, 16, 1), blk, 0, stream>>>(
        xb, wkvb, b_kv, bufB, wqb, b_q, qb, wg1b, b_g1, bufC);
    // 2. gates = softmax(g1 @ W_g2 + b_g2)
    gates_kernel<<<dim3(BS_), dim3(64), 0, stream>>>(bufC, W_g2, b_g2, gates);
    // 3. repack kv fp32 -> Kb, Vt bf16
    repack_kv<<<dim3(B_*H_*16), blk, 0, stream>>>(bufB, Kb, Vt);
    // 4. MFMA flash attention v9 (128 q-rows/block) -> stacked bf16
    attn_mfma9<<<dim3(8 * 144), blk, 0, stream>>>(qb, Kb, Vt, stackedS);
    // 5. h1 partials (bf16): split-K x3 of stacked @ W_m1(bf16) -> bufA
    mfma_gemm<4,1,1><<<dim3(D2_/128, BS_/128, 3), blk, 0, stream>>>(
        stackedS, wmb, b_m1, m1part, BS_, D2_, FD_, FD_/3,
        (long)BS_*D2_, FD_/3, nullptr, nullptr);
    // 5b. repack W_m2 -> wmb (W_m1 copy dead now)
    prepack_w2<<<dim3(1769472/256), blk, 0, stream>>>(W_m2, wmb);
    // 6. h1 = gelu(sum partials + b_m1) -> bf16 bufB
    reduce_m1<<<dim3(BS_*D2_/4/256), blk, 0, stream>>>(m1part, b_m1, h1b);
    // 7. mixed(bf16) = stacked + cross*(h1 @ W_m2(bf16) + b_m2) -> bufA
    mfma_gemm<2,1,1><<<dim3(FD_/128, BS_/128, 1), blk, 0, stream>>>(
        h1b, wmb, b_m2, mixedb, BS_, FD_, D2_, D2_,
        0, 0, stackedS, cross);
    // 8. comb = sum_f mixed*gates -> bf16 bufC (Kb/Vt dead)
    combine_kernel<<<dim3(BS_*(D_/4)/256), blk, 0, stream>>>(mixedb, gates, combb);
    // 9. out partials (fp32): split-K x2 of comb @ W_out(fp32) -> stacked region
    mfma_gemm<4,0,0><<<dim3(D_/128, BS_/128, 2), blk, 0, stream>>>(
        combb, W_out, b_out, outPart, BS_, D_, D_, D_/2,
        (long)BS_*D_, D_/2, nullptr, nullptr);
    // 10. preY = x + partials + b_out, LayerNorm -> d_out (fused)
    reduce_ln<<<dim3(BS_), blk, 0, stream>>>(outPart, b_out, x, ln_g, ln_b, out);
}

// Round 14
// 428.004 us; speedup vs baseline: 1.0349x; 1.0349x over previous
//
#include <hip/hip_runtime.h>
#include <hip/hip_bf16.h>

#define B_ 2
#define S_ 1024
#define D_ 768
#define H_ 12
#define F_ 6
#define DH_ 64
#define BS_ (B_*S_)   // 2048
#define D2_ (2*D_)    // 1536
#define FD_ (F_*D_)   // 4608
#define FD4_ (FD_/4)  // 1152

typedef __attribute__((ext_vector_type(8))) short bf16x8;
typedef __attribute__((ext_vector_type(4))) short bf16x4;
typedef __attribute__((ext_vector_type(4))) float f32x4;

__device__ __forceinline__ float gelu_exact(float x) {
    return 0.5f * x * (1.0f + erff(x * 0.70710678118654752f));
}

// fp32 -> bf16 bits, round-to-nearest-even
__device__ __forceinline__ short f2bf(float f) {
    union { float f; unsigned u; } v; v.f = f;
    unsigned r = v.u + 0x7fff + ((v.u >> 16) & 1);
    return (short)(r >> 16);
}
// truncating fp32->bf16 (1 op)
__device__ __forceinline__ short f2bf_t(float f) {
    return (short)(__float_as_uint(f) >> 16);
}
__device__ __forceinline__ float bf2f(short b) {
    union { unsigned u; float f; } v;
    v.u = ((unsigned)(unsigned short)b) << 16;
    return v.f;
}
// bare v_exp_f32 (2^x, flush-to-zero below 2^-126 — fine for softmax)
__device__ __forceinline__ float fast_exp2(float x) {
#if __has_builtin(__builtin_amdgcn_exp2f)
    return __builtin_amdgcn_exp2f(x);
#else
    float r; asm("v_exp_f32 %0, %1" : "=v"(r) : "v"(x)); return r;
#endif
}

// ===========================================================================
// Shared GEMM tile machinery (128x128 tile, BK=64, 4 waves 2x2, prefetch).
// LDS layout: [tile(8)][kchunk(8)][slot(16)] x 8 shorts, slot = l15^kc^tile.
// ===========================================================================

#define GEMM_STAGE_A16(av)                                                    \
    {                                                                         \
        _Pragma("unroll")                                                     \
        for (int c = 0; c < 4; c++) {                                         \
            const int kc = (akb >> 3) + c;                                    \
            *(bf16x8*)&As[((amt*8 + kc)*16 + ((ar15 ^ kc ^ amt) & 15))*8] = (av)[c]; \
        }                                                                     \
    }

#define GEMM_STAGE_B16(bv)                                                    \
    {                                                                         \
        _Pragma("unroll")                                                     \
        for (int j = 0; j < 4; j++) {                                         \
            const int n  = bn0 + j;                                           \
            const int nt = n >> 4;                                            \
            bf16x8 s;                                                         \
            _Pragma("unroll")                                                 \
            for (int r = 0; r < 8; r++) s[r] = (bv)[r][j];                    \
            *(bf16x8*)&Bs[((nt*8 + bkg)*16 + (((n & 15) ^ bkg ^ nt) & 15))*8] = s; \
        }                                                                     \
    }

#define GEMM_LOAD_A16(av, kb)                                                 \
    {                                                                         \
        _Pragma("unroll")                                                     \
        for (int c = 0; c < 4; c++)                                           \
            (av)[c] = *(const bf16x8*)(Ap + (kb) + c*8);                      \
    }

#define GEMM_LOAD_B16(bv, kb, strideN)                                        \
    {                                                                         \
        _Pragma("unroll")                                                     \
        for (int r = 0; r < 8; r++)                                           \
            *(bf16x4*)&(bv)[r][0] = *(const bf16x4*)(Wp + (long)((kb) + r) * (strideN)); \
    }

#define GEMM_COMPUTE()                                                        \
    {                                                                         \
        _Pragma("unroll")                                                     \
        for (int ks = 0; ks < 2; ks++) {                                      \
            const int kc = ks*4 + quad;                                       \
            bf16x8 af[4], bf[4];                                              \
            _Pragma("unroll")                                                 \
            for (int mt = 0; mt < 4; mt++) {                                  \
                const int MT = wr*4 + mt;                                     \
                af[mt] = *(const bf16x8*)&As[((MT*8 + kc)*16 + ((l15 ^ kc ^ MT) & 15))*8]; \
            }                                                                 \
            _Pragma("unroll")                                                 \
            for (int nt = 0; nt < 4; nt++) {                                  \
                const int NT = wc*4 + nt;                                     \
                bf[nt] = *(const bf16x8*)&Bs[((NT*8 + kc)*16 + ((l15 ^ kc ^ NT) & 15))*8]; \
            }                                                                 \
            _Pragma("unroll")                                                 \
            for (int mt = 0; mt < 4; mt++)                                    \
                _Pragma("unroll")                                             \
                for (int nt = 0; nt < 4; nt++)                                \
                    acc[mt][nt] = __builtin_amdgcn_mfma_f32_16x16x32_bf16(    \
                        af[mt], bf[nt], acc[mt][nt], 0, 0, 0);                \
        }                                                                     \
    }

#define GEMM_COMMON_IDS()                                                     \
    const int tid  = threadIdx.x;                                             \
    const int wave = tid >> 6;                                                \
    const int lane = tid & 63;                                                \
    const int l15  = lane & 15;                                               \
    const int quad = lane >> 4;                                               \
    const int wr   = wave >> 1;                                               \
    const int wc   = wave & 1;                                                \
    const int ar   = tid >> 1;                                                \
    const int akb  = (tid & 1) * 32;                                          \
    const int amt  = ar >> 4;                                                 \
    const int ar15 = ar & 15;                                                 \
    const int bn0  = (tid & 31) * 4;                                          \
    const int bkg  = tid >> 5;

// B load/stage helpers for mfma_gemm (B16: prepacked bf16 W; else fp32 W)
template<int B16>
__device__ __forceinline__ void gemm_load_b(
    const void* __restrict__ Wv, long rowOff, int N, int kb,
    float bf[8][4], short bh[8][4])
{
    if constexpr (B16) {
        const short* Wp = (const short*)Wv + rowOff;
        #pragma unroll
        for (int r = 0; r < 8; r++)
            *(bf16x4*)&bh[r][0] = *(const bf16x4*)(Wp + (long)(kb + r) * N);
    } else {
        const float* Wp = (const float*)Wv + rowOff;
        #pragma unroll
        for (int r = 0; r < 8; r++)
            *(float4*)&bf[r][0] = *(const float4*)(Wp + (long)(kb + r) * N);
    }
}

template<int B16>
__device__ __forceinline__ void gemm_stage_b(
    short* Bs, int bn0, int bkg, const float bf[8][4], const short bh[8][4])
{
    #pragma unroll
    for (int j = 0; j < 4; j++) {
        const int n  = bn0 + j;
        const int nt = n >> 4;
        bf16x8 s;
        #pragma unroll
        for (int r = 0; r < 8; r++) s[r] = B16 ? bh[r][j] : f2bf_t(bf[r][j]);
        *(bf16x8*)&Bs[((nt*8 + bkg)*16 + (((n & 15) ^ bkg ^ nt) & 15))*8] = s;
    }
}

// ---------------------------------------------------------------------------
// prepack: fp32 -> bf16 for x, W_kv, W_q, W_g1, W_m1 (multi-read operands).
// ---------------------------------------------------------------------------
#define PPK_N0 393216    // x        1572864 f /4
#define PPK_N1 294912    // W_kv     1179648 f /4
#define PPK_N2 884736    // W_q      3538944 f /4
#define PPK_N3 221184    // W_g1      884736 f /4
#define PPK_N4 1769472   // W_m1     7077888 f /4
__global__ __launch_bounds__(256) void prepack(
    const float* __restrict__ x, const float* __restrict__ Wkv,
    const float* __restrict__ Wq, const float* __restrict__ Wg1,
    const float* __restrict__ Wm1,
    short* __restrict__ xb, short* __restrict__ wkvb,
    short* __restrict__ wqb, short* __restrict__ wg1b,
    short* __restrict__ wmb)
{
    long idx = (long)blockIdx.x * 256 + threadIdx.x;
    const float* src; short* dst;
    if (idx < PPK_N0) { src = x; dst = xb; }
    else if ((idx -= PPK_N0) < PPK_N1) { src = Wkv; dst = wkvb; }
    else if ((idx -= PPK_N1) < PPK_N2) { src = Wq;  dst = wqb; }
    else if ((idx -= PPK_N2) < PPK_N3) { src = Wg1; dst = wg1b; }
    else { idx -= PPK_N3; src = Wm1; dst = wmb; }
    float4 v = ((const float4*)src)[idx];
    bf16x4 o;
    o[0] = f2bf(v.x); o[1] = f2bf(v.y); o[2] = f2bf(v.z); o[3] = f2bf(v.w);
    ((bf16x4*)dst)[idx] = o;
}

// prepack_w2: W_m2 fp32 -> bf16 into wmb (reuses W_m1's buffer after gemm5)
__global__ __launch_bounds__(256) void prepack_w2(
    const float* __restrict__ Wm2, short* __restrict__ wmb)
{
    long idx = (long)blockIdx.x * 256 + threadIdx.x;
    float4 v = ((const float4*)Wm2)[idx];
    bf16x4 o;
    o[0] = f2bf(v.x); o[1] = f2bf(v.y); o[2] = f2bf(v.z); o[3] = f2bf(v.w);
    ((bf16x4*)wmb)[idx] = o;
}

// ---------------------------------------------------------------------------
// mfma_gemm: bf16 A; W either prepacked bf16 (B16=1) or fp32 (B16=0);
// output bf16 (OUT16=1) or fp32 (OUT16=0).
// MODE 2: C = bf2f(addend) + (*scale_ptr)*v ; MODE 4: raw split-K partial
// ---------------------------------------------------------------------------
template<int MODE, int B16, int OUT16>
__global__ __launch_bounds__(256, 2) void mfma_gemm(
    const short* __restrict__ A, const void* __restrict__ Wv,
    const float* __restrict__ bias, void* __restrict__ Cv,
    int M, int N, int K, int kLen,
    long cStrideZ, long kStrideZ,
    const short* __restrict__ addend, const float* __restrict__ scale_ptr)
{
    short* C16 = (short*)Cv;
    float* C32 = (float*)Cv;
    if (blockIdx.z) { C16 += blockIdx.z * cStrideZ; C32 += blockIdx.z * cStrideZ; }
    const int kBeg = (int)(blockIdx.z * kStrideZ);
    const int kEnd = kBeg + kLen;

    __shared__ __align__(16) short As[8192];
    __shared__ __align__(16) short Bs[8192];

    GEMM_COMMON_IDS();

    const int m0 = blockIdx.y * 128;
    const int n0 = blockIdx.x * 128;

    const short* Ap = A + (long)(m0 + ar) * K + akb;
    const long wRowOff = (long)(bkg * 8) * N + n0 + bn0;

    f32x4 acc[4][4];
    #pragma unroll
    for (int i = 0; i < 4; i++)
        #pragma unroll
        for (int j = 0; j < 4; j++)
            acc[i][j] = (f32x4){0.f, 0.f, 0.f, 0.f};

    bf16x8 a0[4], a1[4];
    float bf0[8][4], bf1[8][4];
    short bh0[8][4], bh1[8][4];
    GEMM_LOAD_A16(a0, kBeg);
    gemm_load_b<B16>(Wv, wRowOff, N, kBeg, bf0, bh0);

    for (int kb = kBeg; kb < kEnd; kb += 128) {
        GEMM_STAGE_A16(a0);
        gemm_stage_b<B16>(Bs, bn0, bkg, bf0, bh0);
        __syncthreads();
        GEMM_LOAD_A16(a1, kb + 64);
        gemm_load_b<B16>(Wv, wRowOff, N, kb + 64, bf1, bh1);
        GEMM_COMPUTE();
        __syncthreads();
        GEMM_STAGE_A16(a1);
        gemm_stage_b<B16>(Bs, bn0, bkg, bf1, bh1);
        __syncthreads();
        if (kb + 128 < kEnd) {
            GEMM_LOAD_A16(a0, kb + 128);
            gemm_load_b<B16>(Wv, wRowOff, N, kb + 128, bf0, bh0);
        }
        GEMM_COMPUTE();
        __syncthreads();
    }

    float scale = 0.0f;
    if (MODE == 2) scale = *scale_ptr;
    #pragma unroll
    for (int nt = 0; nt < 4; nt++) {
        const int col = n0 + wc*64 + nt*16 + l15;
        const float bcol = (MODE == 4) ? 0.0f : bias[col];
        #pragma unroll
        for (int mt = 0; mt < 4; mt++) {
            #pragma unroll
            for (int r = 0; r < 4; r++) {
                const long row = m0 + wr*64 + mt*16 + quad*4 + r;
                float v = acc[mt][nt][r] + bcol;
                if (MODE == 2) v = bf2f(addend[row*N + col]) + scale * v;
                if (OUT16) C16[row*N + col] = f2bf(v);
                else       C32[row*N + col] = v;
            }
        }
    }
}

// ---------------------------------------------------------------------------
// xproj: fused projections of x — all-bf16 operands (prepacked).
//   tiles  0..11 -> kv fp32 [B*S,1536]
//   tiles 12..47 -> q bf16 pre-scaled*(0.125*log2e) -> qb [F][B][H][S][64]
//   tiles 48..56 -> g1 = gelu(..) fp32 [B*S,1152]
// ---------------------------------------------------------------------------
#define QSCALE 0.18033688011112042f   // 0.125 * log2(e)
__global__ __launch_bounds__(256, 2) void xproj_gemm(
    const short* __restrict__ xb,
    const short* __restrict__ W_kv, const float* __restrict__ b_kv, float* __restrict__ bufKV,
    const short* __restrict__ W_q,  const float* __restrict__ b_q,  short* __restrict__ qb,
    const short* __restrict__ W_g1, const float* __restrict__ b_g1, float* __restrict__ bufG1)
{
    __shared__ __align__(16) short As[8192];
    __shared__ __align__(16) short Bs[8192];

    GEMM_COMMON_IDS();

    const int ntile = blockIdx.x;
    const int m0 = blockIdx.y * 128;

    const short* Wseg; const float* bseg; float* Cseg = nullptr;
    int Nw, ncol, fidx = 0, mode;   // mode 0=kv,1=q,2=g1
    if (ntile < 12) {
        Wseg = W_kv; bseg = b_kv; Cseg = bufKV; Nw = 1536; ncol = ntile * 128; mode = 0;
    } else if (ntile < 48) {
        const int t = ntile - 12; fidx = t / 6;
        ncol = (t % 6) * 128;
        Wseg = W_q + (long)fidx * D_ * D_; bseg = b_q + fidx * D_;
        Nw = 768; mode = 1;
    } else {
        const int t = ntile - 48;
        Wseg = W_g1; bseg = b_g1; Cseg = bufG1; Nw = 1152; ncol = t * 128; mode = 2;
    }

    const short* Ap = xb + (long)(m0 + ar) * D_ + akb;
    const short* Wp = Wseg + (long)(bkg * 8) * Nw + ncol + bn0;

    f32x4 acc[4][4];
    #pragma unroll
    for (int i = 0; i < 4; i++)
        #pragma unroll
        for (int j = 0; j < 4; j++)
            acc[i][j] = (f32x4){0.f, 0.f, 0.f, 0.f};

    bf16x8 a0[4], a1[4];
    short b0[8][4], b1[8][4];
    GEMM_LOAD_A16(a0, 0);
    GEMM_LOAD_B16(b0, 0, Nw);

    for (int kb = 0; kb < D_; kb += 128) {
        GEMM_STAGE_A16(a0); GEMM_STAGE_B16(b0);
        __syncthreads();
        GEMM_LOAD_A16(a1, kb + 64);
        GEMM_LOAD_B16(b1, kb + 64, Nw);
        GEMM_COMPUTE();
        __syncthreads();
        GEMM_STAGE_A16(a1); GEMM_STAGE_B16(b1);
        __syncthreads();
        if (kb + 128 < D_) {
            GEMM_LOAD_A16(a0, kb + 128);
            GEMM_LOAD_B16(b0, kb + 128, Nw);
        }
        GEMM_COMPUTE();
        __syncthreads();
    }

    if (mode == 1) {
        const int bb = m0 >> 10;
        const int sBase = (m0 & 1023) + wr*64;
        #pragma unroll
        for (int nt = 0; nt < 4; nt++) {
            const int col = ncol + wc*64 + nt*16 + l15;   // 0..767
            const int hh = col >> 6, dd = col & 63;
            const float bcol = bseg[col];
            short* qBase = qb + ((((long)fidx*B_ + bb)*H_ + hh)*S_)*64 + dd;
            #pragma unroll
            for (int mt = 0; mt < 4; mt++) {
                #pragma unroll
                for (int r = 0; r < 4; r++) {
                    const int s = sBase + mt*16 + quad*4 + r;
                    qBase[(long)s*64] = f2bf((acc[mt][nt][r] + bcol) * QSCALE);
                }
            }
        }
    } else {
        #pragma unroll
        for (int nt = 0; nt < 4; nt++) {
            const int col = ncol + wc*64 + nt*16 + l15;
            const float bcol = bseg[col];
            #pragma unroll
            for (int mt = 0; mt < 4; mt++) {
                #pragma unroll
                for (int r = 0; r < 4; r++) {
                    const long row = m0 + wr*64 + mt*16 + quad*4 + r;
                    float v = acc[mt][nt][r] + bcol;
                    if (mode == 2) v = gelu_exact(v);
                    Cseg[row*Nw + col] = v;
                }
            }
        }
    }
}

// ---------------------------------------------------------------------------
// repack_kv: kv fp32 [B*S,1536] -> Kb bf16 [B][H][S][64], Vt bf16 [B][H][64][S]
// ---------------------------------------------------------------------------
__global__ __launch_bounds__(256) void repack_kv(
    const float* __restrict__ kvf, short* __restrict__ Kb, short* __restrict__ Vtb)
{
    __shared__ __align__(16) short T[64*64];
    const int bx = blockIdx.x;         // b*192 + h*16 + st
    const int st = bx & 15;
    const int h  = (bx >> 4) % 12;
    const int b  = bx / 192;
    const int tid = threadIdx.x;
    const int s_loc = tid & 63;
    const int dch  = (tid >> 6) * 16;
    const int s0 = st * 64;

    const float* kr = kvf + (long)(b*S_ + s0 + s_loc) * D2_ + h*64 + dch;
    float v[16];

    #pragma unroll
    for (int i = 0; i < 4; i++) *(float4*)&v[i*4] = *(const float4*)(kr + i*4);
    {
        short* kw = Kb + ((long)(b*H_ + h)*S_ + s0 + s_loc)*64 + dch;
        bf16x8 p0, p1;
        #pragma unroll
        for (int i = 0; i < 8; i++) { p0[i] = f2bf(v[i]); p1[i] = f2bf(v[8+i]); }
        *(bf16x8*)&kw[0] = p0;
        *(bf16x8*)&kw[8] = p1;
    }

    #pragma unroll
    for (int i = 0; i < 4; i++) *(float4*)&v[i*4] = *(const float4*)(kr + D_ + i*4);
    #pragma unroll
    for (int i = 0; i < 16; i++) {
        const int d = dch + i;
        T[d*64 + ((((s_loc >> 3) ^ d) & 7) << 3) + (s_loc & 7)] = f2bf(v[i]);
    }
    __syncthreads();
    const int d_loc = tid >> 2;
    const int sc = (tid & 3) * 16;
    const int c0 = sc >> 3;
    bf16x8 o0 = *(const bf16x8*)&T[d_loc*64 + (((c0 ^ d_loc) & 7) << 3)];
    bf16x8 o1 = *(const bf16x8*)&T[d_loc*64 + ((((c0+1) ^ d_loc) & 7) << 3)];
    short* vw = Vtb + ((long)(b*H_ + h)*64 + d_loc)*S_ + s0 + sc;
    *(bf16x8*)&vw[0] = o0;
    *(bf16x8*)&vw[8] = o1;
}

// ---------------------------------------------------------------------------
// MFMA flash attention v10: v8 shape (64 q-rows, grid 2304, 24KB LDS) with
// the QK MFMA operand-swapped (S^T = K·Q^T): each lane then holds 4
// CONTIGUOUS keys per q-row, so P-writes collapse from 16 ds_write_b16 to
// 4 packed ds_write_b64 (v_perm pack). P LDS: row-major 16 rows x 128B with
// 16B-granule XOR swizzle (G ^= l15&7): writes/reads <=2-way (free).
// ---------------------------------------------------------------------------
__global__ __launch_bounds__(256, 4) void attn_mfma10(
    const short* __restrict__ qb,
    const short* __restrict__ Kb,
    const short* __restrict__ Vt,
    short* __restrict__ stackedb)
{
    __shared__ __align__(16) short Ks[64*64];
    __shared__ __align__(16) short Vs[64*64];
    __shared__ __align__(16) short Ps[4][16*64];

    const int bx = blockIdx.x;
    const int qt = bx & 15;           // 16 q-tiles of 64 rows
    const int rest = bx >> 4;         // 0..143
    const int h = rest % 12;
    const int r2 = rest / 12;
    const int f = r2 % 6;
    const int b = r2 / 6;

    const int tid  = threadIdx.x;
    const int wave = tid >> 6;
    const int lane = tid & 63;
    const int l15  = lane & 15;
    const int quad = lane >> 4;

    const short* Kg = Kb + (long)(b*H_ + h) * S_ * 64;
    const short* Vg = Vt + (long)(b*H_ + h) * 64 * S_;

    // Q fragment (used as the B operand; A/B register layouts are identical)
    bf16x8 aq[2];
    {
        const short* qp = qb + ((((long)f*B_ + b)*H_ + h)*S_ + qt*64 + wave*16)*64;
        #pragma unroll
        for (int ks = 0; ks < 2; ks++)
            aq[ks] = *(const bf16x8*)&qp[l15*64 + ks*32 + quad*8];
    }

    bf16x8 onesf;
    {
        const short ONE = (short)0x3F80;
        #pragma unroll
        for (int j = 0; j < 8; j++) onesf[j] = (l15 == 0) ? ONE : (short)0;
    }

    const int skey = tid >> 2;         // staging row 0..63
    const int sch  = (tid & 3) * 2;    // chunk pair

    char* Psw = (char*)Ps[wave];

    f32x4 st[4], o[4], lo;
    lo = (f32x4){0.f,0.f,0.f,0.f};
    #pragma unroll
    for (int nt = 0; nt < 4; nt++) o[nt] = (f32x4){0.f,0.f,0.f,0.f};

    bf16x8 kc[2], vc[2], kn[2], vn[2];
    #pragma unroll
    for (int j = 0; j < 2; j++) {
        const int ch = sch + j;
        kc[j] = *(const bf16x8*)&Kg[(long)skey*64 + ch*8];
        vc[j] = *(const bf16x8*)&Vg[(long)skey*S_ + ch*8];
    }

    for (int kt = 0; kt < 16; kt++) {
        #pragma unroll
        for (int j = 0; j < 2; j++) {
            const int ch = sch + j;
            const int slot = ((ch ^ skey) & 7) << 3;
            *(bf16x8*)&Ks[skey*64 + slot] = kc[j];
            *(bf16x8*)&Vs[skey*64 + slot] = vc[j];
        }
        __syncthreads();

        if (kt + 1 < 16) {
            #pragma unroll
            for (int j = 0; j < 2; j++) {
                const int ch = sch + j;
                kn[j] = *(const bf16x8*)&Kg[(long)((kt+1)*64 + skey)*64 + ch*8];
                vn[j] = *(const bf16x8*)&Vg[(long)skey*S_ + (kt+1)*64 + ch*8];
            }
        }

        // ---- S^T = K @ Q^T (K as A, Q as B). C-layout: col=l15 -> q-row,
        //      row=quad*4+r -> key nt*16+quad*4+r ----
        #pragma unroll
        for (int nt = 0; nt < 4; nt++) st[nt] = (f32x4){0.f,0.f,0.f,0.f};
        #pragma unroll
        for (int nt = 0; nt < 4; nt++) {
            const int key = nt*16 + l15;
            #pragma unroll
            for (int ks = 0; ks < 2; ks++) {
                const bf16x8 kf = *(const bf16x8*)
                    &Ks[key*64 + ((((ks*4 + quad) ^ key) & 7) << 3)];
                st[nt] = __builtin_amdgcn_mfma_f32_16x16x32_bf16(kf, aq[ks], st[nt], 0, 0, 0);
            }
        }

        // ---- p = 2^s; pack 4 contiguous keys -> one b64 per nt ----
        // P row = q-row l15 (128B); keys nt*16+quad*4+r. Granule16
        // G = 2*nt + (quad>>1), swizzled G^=(l15&7); low/high 8B by quad&1.
        #pragma unroll
        for (int nt = 0; nt < 4; nt++) {
            const float p0 = fast_exp2(st[nt][0]);
            const float p1 = fast_exp2(st[nt][1]);
            const float p2 = fast_exp2(st[nt][2]);
            const float p3 = fast_exp2(st[nt][3]);
            uint2 pk;
            pk.x = __builtin_amdgcn_perm(__float_as_uint(p1), __float_as_uint(p0), 0x07060302u);
            pk.y = __builtin_amdgcn_perm(__float_as_uint(p3), __float_as_uint(p2), 0x07060302u);
            const int G = 2*nt + (quad >> 1);
            const int off = l15*128 + ((G ^ (l15 & 7)) << 4) + ((quad & 1) << 3);
            *(uint2*)(Psw + off) = pk;
        }

        // ---- P A-fragments (same-wave LDS round-trip) ----
        bf16x8 pa[2];
        #pragma unroll
        for (int ks = 0; ks < 2; ks++) {
            const int c = ks*4 + quad;
            pa[ks] = *(const bf16x8*)(Psw + l15*128 + ((c ^ (l15 & 7)) << 4));
        }

        // ---- O += P @ V ; l += P @ ones ----
        #pragma unroll
        for (int nt = 0; nt < 4; nt++) {
            const int dim = nt*16 + l15;
            #pragma unroll
            for (int ks = 0; ks < 2; ks++) {
                const bf16x8 vf = *(const bf16x8*)
                    &Vs[dim*64 + ((((ks*4 + quad) ^ dim) & 7) << 3)];
                o[nt] = __builtin_amdgcn_mfma_f32_16x16x32_bf16(pa[ks], vf, o[nt], 0, 0, 0);
            }
        }
        #pragma unroll
        for (int ks = 0; ks < 2; ks++)
            lo = __builtin_amdgcn_mfma_f32_16x16x32_bf16(pa[ks], onesf, lo, 0, 0, 0);

        __syncthreads();
        #pragma unroll
        for (int j = 0; j < 2; j++) { kc[j] = kn[j]; vc[j] = vn[j]; }
    }

    float inv[4];
    #pragma unroll
    for (int r = 0; r < 4; r++)
        inv[r] = 1.0f / __shfl(lo[r], quad << 4);
    const long rowBase = (long)(b*S_ + qt*64 + wave*16 + quad*4);
    #pragma unroll
    for (int nt = 0; nt < 4; nt++) {
        #pragma unroll
        for (int r = 0; r < 4; r++) {
            stackedb[(rowBase + r)*FD_ + f*D_ + h*64 + nt*16 + l15] =
                f2bf(o[nt][r] * inv[r]);
        }
    }
}

// ---------------------------------------------------------------------------
// gates[m,f] = softmax_f( g1[m,:] @ W_g2 + b_g2 ), one wave per row
// ---------------------------------------------------------------------------
__global__ __launch_bounds__(64) void gates_kernel(
    const float* __restrict__ g1, const float* __restrict__ W_g2,
    const float* __restrict__ b_g2, float* __restrict__ gates)
{
    const int m = blockIdx.x;
    const int lane = threadIdx.x;
    float p[6] = {0.f,0.f,0.f,0.f,0.f,0.f};
    for (int k = lane; k < FD4_; k += 64) {
        float g = g1[(long)m*FD4_ + k];
        #pragma unroll
        for (int f = 0; f < 6; f++) p[f] += g * W_g2[k*6 + f];
    }
    #pragma unroll
    for (int f = 0; f < 6; f++) {
        float v = p[f];
        #pragma unroll
        for (int off = 1; off < 64; off <<= 1) v += __shfl_xor(v, off);
        p[f] = v + b_g2[f];
    }
    float mx = p[0];
    #pragma unroll
    for (int f = 1; f < 6; f++) mx = fmaxf(mx, p[f]);
    float se = 0.f;
    #pragma unroll
    for (int f = 0; f < 6; f++) { p[f] = expf(p[f] - mx); se += p[f]; }
    const float inv = 1.0f / se;
    if (lane < 6) gates[m*6 + lane] = p[lane] * inv;
}

// ---------------------------------------------------------------------------
// reduce_m1: h1 = gelu(p0+p1+p2+bias) -> bf16 [2048,1536]; partials bf16
// ---------------------------------------------------------------------------
__global__ __launch_bounds__(256) void reduce_m1(
    const short* __restrict__ p, const float* __restrict__ bias,
    short* __restrict__ out)
{
    const int idx = blockIdx.x * 256 + threadIdx.x;
    const int col4 = idx % (D2_/4);
    const long MN4 = (long)BS_ * D2_ / 4;   // bf16x4 units per slice
    bf16x4 a = ((const bf16x4*)p)[idx];
    bf16x4 b = ((const bf16x4*)p)[idx + MN4];
    bf16x4 c = ((const bf16x4*)p)[idx + 2*MN4];
    float4 bb = ((const float4*)bias)[col4];
    bf16x4 o;
    o[0] = f2bf(gelu_exact(bf2f(a[0]) + bf2f(b[0]) + bf2f(c[0]) + bb.x));
    o[1] = f2bf(gelu_exact(bf2f(a[1]) + bf2f(b[1]) + bf2f(c[1]) + bb.y));
    o[2] = f2bf(gelu_exact(bf2f(a[2]) + bf2f(b[2]) + bf2f(c[2]) + bb.z));
    o[3] = f2bf(gelu_exact(bf2f(a[3]) + bf2f(b[3]) + bf2f(c[3]) + bb.w));
    ((bf16x4*)out)[idx] = o;
}

// ---------------------------------------------------------------------------
// comb[m,d] = sum_f mixed[m, f*768+d] * gates[m,f]  ; mixed bf16 -> comb bf16
// ---------------------------------------------------------------------------
__global__ __launch_bounds__(256) void combine_kernel(
    const short* __restrict__ mixedb, const float* __restrict__ gates,
    short* __restrict__ comb)
{
    const int idx = blockIdx.x * 256 + threadIdx.x;
    const int m = idx / 192;
    const int d4 = idx - m*192;
    const bf16x4* mrow = (const bf16x4*)(mixedb + (long)m * FD_);
    float4 a = {0.f,0.f,0.f,0.f};
    #pragma unroll
    for (int f = 0; f < 6; f++) {
        float g = gates[m*6 + f];
        bf16x4 v = mrow[f*192 + d4];
        a.x += g*bf2f(v[0]); a.y += g*bf2f(v[1]);
        a.z += g*bf2f(v[2]); a.w += g*bf2f(v[3]);
    }
    bf16x4 o;
    o[0] = f2bf(a.x); o[1] = f2bf(a.y); o[2] = f2bf(a.z); o[3] = f2bf(a.w);
    ((bf16x4*)comb)[idx] = o;
}

// ---------------------------------------------------------------------------
// reduce_ln: preY = x + p0 + p1 + b_out, then LayerNorm -> out. One block/row.
// ---------------------------------------------------------------------------
__global__ __launch_bounds__(256) void reduce_ln(
    const float* __restrict__ p, const float* __restrict__ bias,
    const float* __restrict__ x,
    const float* __restrict__ ln_g, const float* __restrict__ ln_b,
    float* __restrict__ out)
{
    __shared__ float red[8];
    const int m = blockIdx.x;
    const int tid = threadIdx.x;
    const long MN = (long)BS_ * D_;
    float vals[3];
    float s = 0.f, s2 = 0.f;
    #pragma unroll
    for (int i = 0; i < 3; i++) {
        const int d = tid + 256*i;
        const long o = (long)m*D_ + d;
        float v = x[o] + p[o] + p[MN + o] + bias[d];
        vals[i] = v;
        s += v; s2 += v*v;
    }
    #pragma unroll
    for (int off = 32; off >= 1; off >>= 1) {
        s  += __shfl_xor(s, off);
        s2 += __shfl_xor(s2, off);
    }
    const int wave = tid >> 6;
    if ((tid & 63) == 0) { red[wave*2] = s; red[wave*2+1] = s2; }
    __syncthreads();
    s  = red[0]+red[2]+red[4]+red[6];
    s2 = red[1]+red[3]+red[5]+red[7];
    const float mu  = s * (1.0f/D_);
    const float var = s2 * (1.0f/D_) - mu*mu;
    const float inv = rsqrtf(var + 1e-5f);
    #pragma unroll
    for (int i = 0; i < 3; i++) {
        const int d = tid + 256*i;
        out[(long)m*D_ + d] = (vals[i] - mu) * inv * ln_g[d] + ln_b[d];
    }
}

// ---------------------------------------------------------------------------
extern "C" void kernel_launch(void* const* d_in, const int* in_sizes, int n_in,
                              void* d_out, int out_size, void* d_ws, size_t ws_size,
                              hipStream_t stream)
{
    const float* x     = (const float*)d_in[0];
    const float* W_kv  = (const float*)d_in[1];
    const float* b_kv  = (const float*)d_in[2];
    const float* W_q   = (const float*)d_in[3];
    const float* b_q   = (const float*)d_in[4];
    const float* W_m1  = (const float*)d_in[5];
    const float* b_m1  = (const float*)d_in[6];
    const float* W_m2  = (const float*)d_in[7];
    const float* b_m2  = (const float*)d_in[8];
    const float* cross = (const float*)d_in[9];
    const float* W_g1  = (const float*)d_in[10];
    const float* b_g1  = (const float*)d_in[11];
    const float* W_g2  = (const float*)d_in[12];
    const float* b_g2  = (const float*)d_in[13];
    const float* W_out = (const float*)d_in[14];
    const float* b_out = (const float*)d_in[15];
    const float* ln_g  = (const float*)d_in[16];
    const float* ln_b  = (const float*)d_in[17];
    float* out = (float*)d_out;

    // workspace layout (float units), total ~88.3 MB:
    float* ws       = (float*)d_ws;
    float* bufA     = ws;
    float* bufB     = bufA + (size_t)4718592;
    short* stackedS = (short*)(bufB + (size_t)3145728);
    float* bufC     = (float*)(stackedS + (size_t)BS_*FD_);
    float* gates    = bufC + (size_t)BS_*FD4_;

    short* wpack = (short*)(gates + 12288);
    short* xb    = wpack;                                  // 1,572,864 sh
    short* wkvb  = xb + (size_t)BS_*D_;                    // 1,179,648 sh
    short* wqb   = wkvb + (size_t)D_*D2_;                  // 3,538,944 sh
    short* wg1b  = wqb + (size_t)F_*D_*D_;                 //   884,736 sh
    short* wmb   = wg1b + (size_t)D_*FD4_;                 // 7,077,888 sh

    short* qb      = (short*)bufA;
    short* m1part  = (short*)bufA;     // after qb is dead
    short* mixedb  = (short*)bufA;     // after partials are dead
    short* Kb      = (short*)bufC;
    short* Vt      = Kb + (size_t)B_*H_*S_*DH_;
    short* h1b     = (short*)bufB;
    short* combb   = (short*)bufC;
    float* outPart = (float*)stackedS;

    dim3 blk(256);

    // 0. prepack x + W_kv/W_q/W_g1/W_m1 to bf16
    prepack<<<dim3((PPK_N0+PPK_N1+PPK_N2+PPK_N3+PPK_N4)/256), blk, 0, stream>>>(
        x, W_kv, W_q, W_g1, W_m1, xb, wkvb, wqb, wg1b, wmb);
    // 1. fused x-projections (all-bf16): kv fp32, q bf16 (log2e-scaled), g1 fp32
    xproj_gemm<<<dim3(57, 16, 1), blk, 0, stream>>>(
        xb, wkvb, b_kv, bufB, wqb, b_q, qb, wg1b, b_g1, bufC);
    // 2. gates = softmax(g1 @ W_g2 + b_g2)
    gates_kernel<<<dim3(BS_), dim3(64), 0, stream>>>(bufC, W_g2, b_g2, gates);
    // 3. repack kv fp32 -> Kb, Vt bf16
    repack_kv<<<dim3(B_*H_*16), blk, 0, stream>>>(bufB, Kb, Vt);
    // 4. MFMA flash attention v10 -> stacked bf16
    attn_mfma10<<<dim3(16 * 144), blk, 0, stream>>>(qb, Kb, Vt, stackedS);
    // 5. h1 partials (bf16): split-K x3 of stacked @ W_m1(bf16) -> bufA
    mfma_gemm<4,1,1><<<dim3(D2_/128, BS_/128, 3), blk, 0, stream>>>(
        stackedS, wmb, b_m1, m1part, BS_, D2_, FD_, FD_/3,
        (long)BS_*D2_, FD_/3, nullptr, nullptr);
    // 5b. repack W_m2 -> wmb (W_m1 copy dead now)
    prepack_w2<<<dim3(1769472/256), blk, 0, stream>>>(W_m2, wmb);
    // 6. h1 = gelu(sum partials + b_m1) -> bf16 bufB
    reduce_m1<<<dim3(BS_*D2_/4/256), blk, 0, stream>>>(m1part, b_m1, h1b);
    // 7. mixed(bf16) = stacked + cross*(h1 @ W_m2(bf16) + b_m2) -> bufA
    mfma_gemm<2,1,1><<<dim3(FD_/128, BS_/128, 1), blk, 0, stream>>>(
        h1b, wmb, b_m2, mixedb, BS_, FD_, D2_, D2_,
        0, 0, stackedS, cross);
    // 8. comb = sum_f mixed*gates -> bf16 bufC (Kb/Vt dead)
    combine_kernel<<<dim3(BS_*(D_/4)/256), blk, 0, stream>>>(mixedb, gates, combb);
    // 9. out partials (fp32): split-K x2 of comb @ W_out(fp32) -> stacked region
    mfma_gemm<4,0,0><<<dim3(D_/128, BS_/128, 2), blk, 0, stream>>>(
        combb, W_out, b_out, outPart, BS_, D_, D_, D_/2,
        (long)BS_*D_, D_/2, nullptr, nullptr);
    // 10. preY = x + partials + b_out, LayerNorm -> d_out (fused)
    reduce_ln<<<dim3(BS_), blk, 0, stream>>>(outPart, b_out, x, ln_g, ln_b, out);
}